// Round 8
// baseline (108.177 us; speedup 1.0000x reference)
//
#include <hip/hip_runtime.h>

// CatNet_76553497084407 — SLAYER-style spiking CNN, fully collapsed over time.
//
// Only spike COUNTS flow between layers, so T=50 is never materialized.
// R7: conv2+pool+rate fused (one 10-tap window per pool output) — but the
// stride-2 window reads doubled LDS bank conflicts (2.05M), net neutral.
// R8: (a) r1 stored as even/odd split arrays -> fused window reads become
// stride-1 (conflict-free), same values/order (bit-identical);
// (b) conv3 at 8 out-ch/thread on 8 waves -> half the LDS read instructions.
// R4-R6 lesson: no wide-unrolled b128 windows (VGPR cap 64 -> scratch spill).

#define T_STEPS 50
#define THETA   0.9999f

__device__ __forceinline__ float spike_rate(float a) {
    constexpr float INV = 50.0f / 0.9999f;
    float t = a * INV;
    float c = fminf(fmaxf(floorf(t), 0.0f), 50.0f);
    // fall back to the exact 50-step f32 sim when t is near an integer
    bool risky = (t > 0.5f) && (fabsf(t - rintf(t)) < 5e-4f);
    if (__ballot(risky)) {
        float v = 0.f, cnt = 0.f;
#pragma unroll 1
        for (int k = 0; k < T_STEPS; ++k) {
            v += a;
            float s = (v >= THETA) ? 1.0f : 0.0f;
            v -= s * THETA;
            cnt += s;
        }
        c = cnt;
    }
    return c / 50.0f;   // true divide: match reference sum/T rounding
}

extern "C" __global__ void __launch_bounds__(1024)
catnet_kernel(const float* __restrict__ x,
              const float* __restrict__ w1, const float* __restrict__ b1,
              const float* __restrict__ w2, const float* __restrict__ b2,
              const float* __restrict__ w3, const float* __restrict__ b3,
              const float* __restrict__ wf, const float* __restrict__ bf,
              float* __restrict__ out)
{
    const int n    = blockIdx.x;
    const int tid  = threadIdx.x;
    const int wave = tid >> 6;
    const int lane = tid & 63;

    __shared__ float xbar[182];        // padded time-summed input
    __shared__ float r1e[16][91];      // r1 at even padded idx 2k
    __shared__ float r1o[16][91];      // r1 at odd  padded idx 2k+1
    __shared__ float r3p[32][89];      // [c][p+1], zero-padded borders
    __shared__ float r4s[32][83];
    __shared__ float part[16];

    // zero pads: r1e[c][0] <- pidx0, r1o[c][90] <- pidx181, r3p borders
    if (tid < 16)              { r1e[tid][0] = 0.f; r1o[tid][90] = 0.f; }
    if (tid >= 32 && tid < 64) { r3p[tid-32][0] = 0.f; r3p[tid-32][88] = 0.f; }
    if (tid == 64)             { xbar[0] = 0.f; xbar[181] = 0.f; }

    // ---- phase 0: time-sum of input, 4 lanes per h ----
    const float* xn = x + (size_t)n * (180 * 50);
    if (tid < 720) {
        const int h = tid >> 2, q = tid & 3;
        const float* row = xn + h * 50;
        float s = 0.f;
        for (int t = q; t < T_STEPS; t += 4) s += row[t];
        s += __shfl_xor(s, 1, 4);
        s += __shfl_xor(s, 2, 4);
        if (q == 0) xbar[h + 1] = s;
    }
    __syncthreads();

    // ---- phase 1: conv1 (1->16, k=3, pad=1), /T, +b1, rate -> r1e/r1o ----
    for (int idx = tid; idx < 16 * 180; idx += 1024) {
        int c = idx / 180, h = idx - c * 180;
        float a = w1[c*3+0] * xbar[h] + w1[c*3+1] * xbar[h+1] + w1[c*3+2] * xbar[h+2];
        a = a / 50.0f + b1[c];
        float r = spike_rate(a);
        int pidx = h + 1;
        float* dst = (pidx & 1) ? &r1o[c][pidx >> 1] : &r1e[c][pidx >> 1];
        *dst = r;
    }
    __syncthreads();

    // ---- phase 2: conv2 (16->32, k=9, pad=1) + rate + pool(2)*1.1 + rate ----
    // 8 groups of 128 threads (g wave-uniform); thread -> pool output p.
    // 10-tap window (padded pidx 2p..2p+9) = r1e[p..p+4] + r1o[p..p+4]:
    // stride-1 lane addressing, conflict-free.
    {
        const int g   = __builtin_amdgcn_readfirstlane(tid >> 7);   // 0..7
        const int p   = tid & 127;
        const bool act = p < 87;
        const int pr  = act ? p : 0;
        const float* wb = w2 + g * 4 * 144;   // [j][ci][kh], j stride 144

        float a0[4], a1[4];
#pragma unroll
        for (int j = 0; j < 4; ++j) { a0[j] = b2[g*4 + j]; a1[j] = a0[j]; }

        for (int ci = 0; ci < 16; ++ci) {
            float we[5], wo[5];
#pragma unroll
            for (int d = 0; d < 5; ++d) {
                we[d] = r1e[ci][pr + d];
                wo[d] = r1o[ci][pr + d];
            }
#pragma unroll
            for (int j = 0; j < 4; ++j) {
                const float* wj = wb + j * 144 + ci * 9;
                // conv at h=2p: taps pidx 2p+kh, kh=0..8 (kh order preserved)
                a0[j] += wj[0]*we[0] + wj[1]*wo[0] + wj[2]*we[1] + wj[3]*wo[1]
                       + wj[4]*we[2] + wj[5]*wo[2] + wj[6]*we[3] + wj[7]*wo[3]
                       + wj[8]*we[4];
                // conv at h=2p+1: taps pidx 2p+1+kh
                a1[j] += wj[0]*wo[0] + wj[1]*we[1] + wj[2]*wo[1] + wj[3]*we[2]
                       + wj[4]*wo[2] + wj[5]*we[3] + wj[6]*wo[3] + wj[7]*we[4]
                       + wj[8]*wo[4];
            }
        }
#pragma unroll
        for (int j = 0; j < 4; ++j) {
            float r20 = spike_rate(a0[j]);
            float r21 = spike_rate(a1[j]);
            float r3  = spike_rate(1.1f * (r20 + r21));
            if (act) r3p[g*4 + j][p + 1] = r3;
        }
    }
    __syncthreads();

    // ---- phase 4: conv3 (32->32, k=7, pad=1) + rate ----
    // 8 waves = 4 out-ch-groups(8) x 2 h-halves; lanes -> h (stride-1 reads).
    // 8 out-ch/thread halves total LDS read instructions vs 4/thread.
    if (wave < 8) {
        const int g8   = __builtin_amdgcn_readfirstlane((wave >> 1) * 8);
        const int half = wave & 1;
        const int cnt  = half ? 41 : 42;
        const bool act = lane < cnt;
        const int h0   = half * 42 + lane;    // valid max 82; window max 88
        const int hr   = act ? h0 : 0;

        float a[8];
#pragma unroll
        for (int j = 0; j < 8; ++j) a[j] = b3[g8 + j];

        for (int ci = 0; ci < 32; ++ci) {
            float rv[7];
#pragma unroll
            for (int kh = 0; kh < 7; ++kh) rv[kh] = r3p[ci][hr + kh];
#pragma unroll
            for (int j = 0; j < 8; ++j) {
                const float* wj = w3 + ((g8 + j) * 32 + ci) * 7;
#pragma unroll
                for (int kh = 0; kh < 7; ++kh)
                    a[j] += wj[kh] * rv[kh];
            }
        }
#pragma unroll
        for (int j = 0; j < 8; ++j) {
            float r = spike_rate(a[j]);
            if (act) r4s[g8 + j][h0] = r;
        }
    }
    __syncthreads();

    // ---- phase 5: dense [32*83] -> 4 outputs; 4 waves per output ----
    {
        const int o = wave >> 2, q = wave & 3;
        const float* r4f = &r4s[0][0];
        const float* wo  = wf + o * (32 * 83);
        float acc = 0.f;
        for (int j = q * 64 + lane; j < 32 * 83; j += 256)
            acc += r4f[j] * wo[j];
#pragma unroll
        for (int off = 32; off > 0; off >>= 1)
            acc += __shfl_down(acc, off, 64);
        if (lane == 0) part[wave] = acc;
    }
    __syncthreads();
    if (tid < 4) {
        float s = part[tid*4] + part[tid*4+1] + part[tid*4+2] + part[tid*4+3];
        out[n * 4 + tid] = s + bf[tid];
    }
}

extern "C" void kernel_launch(void* const* d_in, const int* in_sizes, int n_in,
                              void* d_out, int out_size, void* d_ws, size_t ws_size,
                              hipStream_t stream) {
    const float* x  = (const float*)d_in[0];
    const float* w1 = (const float*)d_in[1];
    const float* b1 = (const float*)d_in[2];
    const float* w2 = (const float*)d_in[3];
    const float* b2 = (const float*)d_in[4];
    const float* w3 = (const float*)d_in[5];
    const float* b3 = (const float*)d_in[6];
    const float* wf = (const float*)d_in[7];
    const float* bf = (const float*)d_in[8];
    float* outp = (float*)d_out;

    catnet_kernel<<<dim3(256), dim3(1024), 0, stream>>>(
        x, w1, b1, w2, b2, w3, b3, wf, bf, outp);
}

// Round 9
// 104.916 us; speedup vs baseline: 1.0311x; 1.0311x over previous
//
#include <hip/hip_runtime.h>

// CatNet_76553497084407 — SLAYER-style spiking CNN, fully collapsed over time.
//
// Only spike COUNTS flow between layers, so T=50 is never materialized.
// R8a (kept): r1 even/odd split -> fused conv2+pool window reads are
//   stride-1, conflict-free (conflicts 2.05M -> 591K). Bit-identical taps.
// R8b (reverted): conv3 on 8 waves was latency-bound (2 waves/SIMD can't
//   hide the ci-loop smem+LDS chains) — back to R7's 16-wave mapping.
// R9: float2-vectorized phase 0 (rows are 200B -> always 8B-aligned);
//   #pragma unroll 2 on conv ci-loops to pipeline window loads vs FMAs.
// R4-R6 lesson: no full-unrolled wide windows (load hoisting -> VGPR cap 64
//   -> scratch spill, WRITE_SIZE 190-232MB). Watch WRITE_SIZE ~8KB.

#define T_STEPS 50
#define THETA   0.9999f

__device__ __forceinline__ float spike_rate(float a) {
    constexpr float INV = 50.0f / 0.9999f;
    float t = a * INV;
    float c = fminf(fmaxf(floorf(t), 0.0f), 50.0f);
    // fall back to the exact 50-step f32 sim when t is near an integer
    bool risky = (t > 0.5f) && (fabsf(t - rintf(t)) < 5e-4f);
    if (__ballot(risky)) {
        float v = 0.f, cnt = 0.f;
#pragma unroll 1
        for (int k = 0; k < T_STEPS; ++k) {
            v += a;
            float s = (v >= THETA) ? 1.0f : 0.0f;
            v -= s * THETA;
            cnt += s;
        }
        c = cnt;
    }
    return c / 50.0f;   // true divide: match reference sum/T rounding
}

extern "C" __global__ void __launch_bounds__(1024)
catnet_kernel(const float* __restrict__ x,
              const float* __restrict__ w1, const float* __restrict__ b1,
              const float* __restrict__ w2, const float* __restrict__ b2,
              const float* __restrict__ w3, const float* __restrict__ b3,
              const float* __restrict__ wf, const float* __restrict__ bf,
              float* __restrict__ out)
{
    const int n    = blockIdx.x;
    const int tid  = threadIdx.x;
    const int wave = tid >> 6;
    const int lane = tid & 63;

    __shared__ float xbar[182];        // padded time-summed input
    __shared__ float r1e[16][91];      // r1 at even padded idx 2k
    __shared__ float r1o[16][91];      // r1 at odd  padded idx 2k+1
    __shared__ float r3p[32][89];      // [c][p+1], zero-padded borders
    __shared__ float r4s[32][83];
    __shared__ float part[16];

    // zero pads: r1e[c][0] <- pidx0, r1o[c][90] <- pidx181, r3p borders
    if (tid < 16)              { r1e[tid][0] = 0.f; r1o[tid][90] = 0.f; }
    if (tid >= 32 && tid < 64) { r3p[tid-32][0] = 0.f; r3p[tid-32][88] = 0.f; }
    if (tid == 64)             { xbar[0] = 0.f; xbar[181] = 0.f; }

    // ---- phase 0: time-sum of input, 4 lanes per h, float2 loads ----
    // row = 50 floats = 200 B -> every row 8B-aligned; 25 float2 chunks.
    const float* xn = x + (size_t)n * (180 * 50);
    if (tid < 720) {
        const int h = tid >> 2, q = tid & 3;
        const float2* row = (const float2*)(xn + h * 50);
        float s = 0.f;
        for (int k = q; k < 25; k += 4) {
            float2 v = row[k];
            s += v.x + v.y;
        }
        s += __shfl_xor(s, 1, 4);
        s += __shfl_xor(s, 2, 4);
        if (q == 0) xbar[h + 1] = s;
    }
    __syncthreads();

    // ---- phase 1: conv1 (1->16, k=3, pad=1), /T, +b1, rate -> r1e/r1o ----
    for (int idx = tid; idx < 16 * 180; idx += 1024) {
        int c = idx / 180, h = idx - c * 180;
        float a = w1[c*3+0] * xbar[h] + w1[c*3+1] * xbar[h+1] + w1[c*3+2] * xbar[h+2];
        a = a / 50.0f + b1[c];
        float r = spike_rate(a);
        int pidx = h + 1;
        float* dst = (pidx & 1) ? &r1o[c][pidx >> 1] : &r1e[c][pidx >> 1];
        *dst = r;
    }
    __syncthreads();

    // ---- phase 2: conv2 (16->32, k=9, pad=1) + rate + pool(2)*1.1 + rate ----
    // 8 groups of 128 threads (g wave-uniform); thread -> pool output p.
    // 10-tap window (padded pidx 2p..2p+9) = r1e[p..p+4] + r1o[p..p+4]:
    // stride-1 lane addressing, conflict-free.
    {
        const int g   = __builtin_amdgcn_readfirstlane(tid >> 7);   // 0..7
        const int p   = tid & 127;
        const bool act = p < 87;
        const int pr  = act ? p : 0;
        const float* wb = w2 + g * 4 * 144;   // [j][ci][kh], j stride 144

        float a0[4], a1[4];
#pragma unroll
        for (int j = 0; j < 4; ++j) { a0[j] = b2[g*4 + j]; a1[j] = a0[j]; }

#pragma unroll 2
        for (int ci = 0; ci < 16; ++ci) {
            float we[5], wo[5];
#pragma unroll
            for (int d = 0; d < 5; ++d) {
                we[d] = r1e[ci][pr + d];
                wo[d] = r1o[ci][pr + d];
            }
#pragma unroll
            for (int j = 0; j < 4; ++j) {
                const float* wj = wb + j * 144 + ci * 9;
                // conv at h=2p: taps pidx 2p+kh, kh=0..8 (kh order preserved)
                a0[j] += wj[0]*we[0] + wj[1]*wo[0] + wj[2]*we[1] + wj[3]*wo[1]
                       + wj[4]*we[2] + wj[5]*wo[2] + wj[6]*we[3] + wj[7]*wo[3]
                       + wj[8]*we[4];
                // conv at h=2p+1: taps pidx 2p+1+kh
                a1[j] += wj[0]*wo[0] + wj[1]*we[1] + wj[2]*wo[1] + wj[3]*we[2]
                       + wj[4]*wo[2] + wj[5]*we[3] + wj[6]*wo[3] + wj[7]*we[4]
                       + wj[8]*wo[4];
            }
        }
#pragma unroll
        for (int j = 0; j < 4; ++j) {
            float r20 = spike_rate(a0[j]);
            float r21 = spike_rate(a1[j]);
            float r3  = spike_rate(1.1f * (r20 + r21));
            if (act) r3p[g*4 + j][p + 1] = r3;
        }
    }
    __syncthreads();

    // ---- phase 4: conv3 (32->32, k=7, pad=1) + rate ----
    // 16 waves = 8 out-ch-groups(4) x 2 h-halves; lanes -> h (stride-1 reads).
    {
        const int g4   = __builtin_amdgcn_readfirstlane((wave >> 1) * 4);
        const int half = wave & 1;
        const int cnt  = half ? 41 : 42;
        const bool act = lane < cnt;
        const int h0   = half * 42 + lane;    // valid max 82; window max 88
        const int hr   = act ? h0 : 0;
        const float* wb = w3 + g4 * 224;      // [j][ci][kh], j stride 224

        float a[4];
#pragma unroll
        for (int j = 0; j < 4; ++j) a[j] = b3[g4 + j];

#pragma unroll 2
        for (int ci = 0; ci < 32; ++ci) {
            float rv[7];
#pragma unroll
            for (int kh = 0; kh < 7; ++kh) rv[kh] = r3p[ci][hr + kh];
#pragma unroll
            for (int j = 0; j < 4; ++j) {
                const float* wj = wb + j * 224 + ci * 7;
#pragma unroll
                for (int kh = 0; kh < 7; ++kh)
                    a[j] += wj[kh] * rv[kh];
            }
        }
#pragma unroll
        for (int j = 0; j < 4; ++j) {
            float r = spike_rate(a[j]);
            if (act) r4s[g4 + j][h0] = r;
        }
    }
    __syncthreads();

    // ---- phase 5: dense [32*83] -> 4 outputs; 4 waves per output ----
    {
        const int o = wave >> 2, q = wave & 3;
        const float* r4f = &r4s[0][0];
        const float* wo  = wf + o * (32 * 83);
        float acc = 0.f;
        for (int j = q * 64 + lane; j < 32 * 83; j += 256)
            acc += r4f[j] * wo[j];
#pragma unroll
        for (int off = 32; off > 0; off >>= 1)
            acc += __shfl_down(acc, off, 64);
        if (lane == 0) part[wave] = acc;
    }
    __syncthreads();
    if (tid < 4) {
        float s = part[tid*4] + part[tid*4+1] + part[tid*4+2] + part[tid*4+3];
        out[n * 4 + tid] = s + bf[tid];
    }
}

extern "C" void kernel_launch(void* const* d_in, const int* in_sizes, int n_in,
                              void* d_out, int out_size, void* d_ws, size_t ws_size,
                              hipStream_t stream) {
    const float* x  = (const float*)d_in[0];
    const float* w1 = (const float*)d_in[1];
    const float* b1 = (const float*)d_in[2];
    const float* w2 = (const float*)d_in[3];
    const float* b2 = (const float*)d_in[4];
    const float* w3 = (const float*)d_in[5];
    const float* b3 = (const float*)d_in[6];
    const float* wf = (const float*)d_in[7];
    const float* bf = (const float*)d_in[8];
    float* outp = (float*)d_out;

    catnet_kernel<<<dim3(256), dim3(1024), 0, stream>>>(
        x, w1, b1, w2, b2, w3, b3, wf, bf, outp);
}